// Round 3
// baseline (912.729 us; speedup 1.0000x reference)
//
#include <hip/hip_runtime.h>
#include <hip/hip_bf16.h>
#include <math.h>

#define NSEG 25000
#define NPTS 500000
#define S_RFF 0.08838834764831845f   // sqrt(2/256)

typedef __attribute__((ext_vector_type(8))) short v8s;
typedef __attribute__((ext_vector_type(4))) float v4f;

#define MF(a,b,c) __builtin_amdgcn_mfma_f32_16x16x32_bf16(a,b,c,0,0,0)

// ---- d_ws plane offsets (A-fragment order, transposed weights) ----
#define W1 0          // Om0^T  [mt 16][kcg 2][pl 2(hi,lo)] x 1KB = 64KB   (no pi)
#define W2 65536      // Wm0^T  [kc 8][mt 8][pl 3(hi,lo,E)] x 1KB = 192KB (pi)
#define W3 262144     // Om1^T  [kc 4][mt 16][pl 3(hi,lo,S)] x 1KB = 192KB (pi)
#define W4 458752     // Wm1^T  [kc 8][dt 4][pl 2(hi,E)] x 1KB = 64KB     (pi)
// total 512KB

__device__ __forceinline__ ushort bf16_rne(float f) {
    uint u = __builtin_bit_cast(uint, f);
    u += 0x7fffu + ((u >> 16) & 1u);
    return (ushort)(u >> 16);
}
__device__ __forceinline__ float bf16f(ushort h) {
    uint u = ((uint)h) << 16;
    return __builtin_bit_cast(float, u);
}
__device__ __forceinline__ uint pk2(float a, float b) {
    __hip_bfloat162 h = __float22bfloat162_rn(make_float2(a, b));
    union { __hip_bfloat162 h; uint u; } c; c.h = h; return c.u;
}
__device__ __forceinline__ v8s mk8(uint a, uint b, uint c, uint d) {
    union { uint u[4]; v8s v; } x; x.u[0]=a; x.u[1]=b; x.u[2]=c; x.u[3]=d; return x.v;
}
__device__ __forceinline__ void unpk2(uint u, float& a, float& b) {
    a = __builtin_bit_cast(float, u << 16);
    b = __builtin_bit_cast(float, u & 0xffff0000u);
}

// slot position for k-permuted A-frags: B-side provides k = 4g+j (j<4) / 16+4g+(j-4)
__device__ __forceinline__ int pi_el(int k32, int row) {
    int gk, j;
    if (k32 < 16) { gk = k32 >> 2; j = k32 & 3; }
    else          { gk = (k32 - 16) >> 2; j = 4 + ((k32 - 16) & 3); }
    return (gk * 16 + row) * 8 + j;
}

// ---------- prep: weights -> transposed A-fragment planes ----------
__global__ void dgp_prep(const float* __restrict__ Om0, const float* __restrict__ Wm0,
                         const float* __restrict__ Wlv0, const float* __restrict__ Om1,
                         const float* __restrict__ Wm1, const float* __restrict__ Wlv1,
                         char* __restrict__ ws)
{
    const int idx = blockIdx.x * 256 + threadIdx.x;   // 0..32767
    // W1: Om0 [64][256], straight slot order (B-side x is loaded straight)
    if (idx < 16384) {
        int k = idx >> 8, c = idx & 255;
        int kcg = k >> 5, k32 = k & 31, mt = c >> 4, row = c & 15;
        int el = ((k32 >> 3) * 16 + row) * 8 + (k32 & 7);
        float v = Om0[idx];
        ushort hi = bf16_rne(v), lo = bf16_rne(v - bf16f(hi));
        ushort* p = (ushort*)(ws + W1);
        int t0 = (mt * 2 + kcg) * 2;
        p[(size_t)t0 * 512 + el] = hi;
        p[(size_t)(t0 + 1) * 512 + el] = lo;
    }
    // W2: Wm0 [256][128] + exp(Wlv0), pi
    {
        int k = idx >> 7, n = idx & 127;
        int kc = k >> 5, k32 = k & 31, mt = n >> 4, row = n & 15;
        int el = pi_el(k32, row);
        float v = Wm0[idx];
        ushort hi = bf16_rne(v), lo = bf16_rne(v - bf16f(hi));
        ushort* p = (ushort*)(ws + W2);
        int t0 = (kc * 8 + mt) * 3;
        p[(size_t)t0 * 512 + el] = hi;
        p[(size_t)(t0 + 1) * 512 + el] = lo;
        p[(size_t)(t0 + 2) * 512 + el] = bf16_rne(expf(Wlv0[idx]));
    }
    // W3: Om1 [128][256] hi/lo + Om1^2, pi
    {
        int k = idx >> 8, c = idx & 255;
        int kc = k >> 5, k32 = k & 31, mt = c >> 4, row = c & 15;
        int el = pi_el(k32, row);
        float v = Om1[idx];
        ushort hi = bf16_rne(v), lo = bf16_rne(v - bf16f(hi));
        ushort* p = (ushort*)(ws + W3);
        int t0 = (kc * 16 + mt) * 3;
        p[(size_t)t0 * 512 + el] = hi;
        p[(size_t)(t0 + 1) * 512 + el] = lo;
        p[(size_t)(t0 + 2) * 512 + el] = bf16_rne(v * v);
    }
    // W4: Wm1 [256][64] + exp(Wlv1), pi
    if (idx < 16384) {
        int k = idx >> 6, d = idx & 63;
        int kc = k >> 5, k32 = k & 31, dt = d >> 4, row = d & 15;
        int el = pi_el(k32, row);
        ushort* p = (ushort*)(ws + W4);
        int t0 = (kc * 4 + dt) * 2;
        p[(size_t)t0 * 512 + el] = bf16_rne(Wm1[idx]);
        p[(size_t)(t0 + 1) * 512 + el] = bf16_rne(expf(Wlv1[idx]));
    }
}

// ---------- weight-chunk staging (global -> LDS, linear, 16B/lane) ----------
typedef __attribute__((address_space(1))) const unsigned int g_u32;
typedef __attribute__((address_space(3))) unsigned int l_u32;

template <int NKB>
__device__ __forceinline__ void stage_kb(const char* gsrc, char* dst, int w, int l) {
    #pragma unroll
    for (int i = 0; i < NKB / 4; ++i) {
        int o = (i * 4 + w) * 1024;
        __builtin_amdgcn_global_load_lds((g_u32*)(gsrc + o + l * 16),
                                         (l_u32*)(dst + o), 16, 0, 0);
    }
}

// ---------- fused main: 4 waves x 32 pts, activations never leave registers ----------
__global__ __launch_bounds__(256, 2)
void dgp_main(const float* __restrict__ x, const int* __restrict__ xidx,
              const float* __restrict__ b0, const float* __restrict__ b1,
              const char* __restrict__ ws,
              float* __restrict__ sum_wm, float* __restrict__ sum_inv)
{
    __shared__ __attribute__((aligned(16))) char lds[49152];   // 2 x 24KB ring
    const int t = threadIdx.x, l = t & 63, w = t >> 6;
    const int r16 = l & 15, g = l >> 4;
    const int base = blockIdx.x * 128 + w * 32;

    const v4f zf = {0.f, 0.f, 0.f, 0.f};

    // ---- x B-frags (hi/lo, 2 sets x 2 K-chunks) ----
    v8s xh[2][2], xl[2][2];
    #pragma unroll
    for (int st = 0; st < 2; ++st) {
        int pc = min(base + st * 16 + r16, NPTS - 1);
        #pragma unroll
        for (int kcg = 0; kcg < 2; ++kcg) {
            const float* xp = x + (size_t)pc * 64 + kcg * 32 + g * 8;
            float4 a = *(const float4*)xp;
            float4 b = *(const float4*)(xp + 4);
            uint h0 = pk2(a.x, a.y), h1 = pk2(a.z, a.w), h2 = pk2(b.x, b.y), h3 = pk2(b.z, b.w);
            float q0,q1,q2,q3,q4,q5,q6,q7;
            unpk2(h0,q0,q1); unpk2(h1,q2,q3); unpk2(h2,q4,q5); unpk2(h3,q6,q7);
            xh[st][kcg] = mk8(h0, h1, h2, h3);
            xl[st][kcg] = mk8(pk2(a.x-q0, a.y-q1), pk2(a.z-q2, a.w-q3),
                              pk2(b.x-q4, b.y-q5), pk2(b.z-q6, b.w-q7));
        }
    }

    v4f am[2][8], av[2][8];
    #pragma unroll
    for (int st = 0; st < 2; ++st)
        #pragma unroll
        for (int nt = 0; nt < 8; ++nt) { am[st][nt] = zf; av[st][nt] = zf; }

    // ================= layer 0: 8 phases (G1 mt-pair + G2 K-chunk) =================
    stage_kb<24>(ws + W2, lds, w, l);
    __syncthreads();

    for (int kc = 0; kc < 8; ++kc) {
        char* buf = lds + (kc & 1) * 24576;
        if (kc < 7)
            stage_kb<24>(ws + W2 + (size_t)(kc + 1) * 24576, lds + ((kc + 1) & 1) * 24576, w, l);

        // G1: z0^T for mt-pair {2kc, 2kc+1}; A=Om0^T from global (L1/L2-hot), 3-term
        v4f z[2][2] = {{zf, zf}, {zf, zf}};
        #pragma unroll
        for (int tt = 0; tt < 2; ++tt) {
            int mt = 2 * kc + tt;
            #pragma unroll
            for (int kcg = 0; kcg < 2; ++kcg) {
                const char* wp = ws + W1 + (size_t)((mt * 2 + kcg) * 2) * 1024 + l * 16;
                v8s ah = *(const v8s*)wp;
                v8s al = *(const v8s*)(wp + 1024);
                #pragma unroll
                for (int st = 0; st < 2; ++st) {
                    v4f a = z[st][tt];
                    a = MF(ah, xh[st][kcg], a);
                    a = MF(al, xh[st][kcg], a);
                    a = MF(ah, xl[st][kcg], a);
                    z[st][tt] = a;
                }
            }
        }
        // phi0 = s*cos(z+b0) -> B-frags (hi + sq), in-register
        float4 bbA = *(const float4*)(b0 + (2 * kc) * 16 + 4 * g);
        float4 bbB = *(const float4*)(b0 + (2 * kc + 1) * 16 + 4 * g);
        v8s ph[2], psq[2];
        #pragma unroll
        for (int st = 0; st < 2; ++st) {
            float pA[4], pB[4];
            pA[0] = S_RFF * __cosf(z[st][0][0] + bbA.x);
            pA[1] = S_RFF * __cosf(z[st][0][1] + bbA.y);
            pA[2] = S_RFF * __cosf(z[st][0][2] + bbA.z);
            pA[3] = S_RFF * __cosf(z[st][0][3] + bbA.w);
            pB[0] = S_RFF * __cosf(z[st][1][0] + bbB.x);
            pB[1] = S_RFF * __cosf(z[st][1][1] + bbB.y);
            pB[2] = S_RFF * __cosf(z[st][1][2] + bbB.z);
            pB[3] = S_RFF * __cosf(z[st][1][3] + bbB.w);
            ph[st]  = mk8(pk2(pA[0], pA[1]), pk2(pA[2], pA[3]),
                          pk2(pB[0], pB[1]), pk2(pB[2], pB[3]));
            psq[st] = mk8(pk2(pA[0]*pA[0], pA[1]*pA[1]), pk2(pA[2]*pA[2], pA[3]*pA[3]),
                          pk2(pB[0]*pB[0], pB[1]*pB[1]), pk2(pB[2]*pB[2], pB[3]*pB[3]));
        }
        // G2: m0/v0 accumulate; A=Wm0^T from LDS chunk (2-term mean + var)
        #pragma unroll
        for (int nt = 0; nt < 8; ++nt) {
            const char* bp = buf + nt * 3072 + l * 16;
            v8s wh = *(const v8s*)bp;
            v8s wl = *(const v8s*)(bp + 1024);
            v8s we = *(const v8s*)(bp + 2048);
            #pragma unroll
            for (int st = 0; st < 2; ++st) {
                v4f a = am[st][nt];
                a = MF(wh, ph[st], a);
                a = MF(wl, ph[st], a);
                am[st][nt] = a;
                av[st][nt] = MF(we, psq[st], av[st][nt]);
            }
        }
        __syncthreads();
    }

    // ---- transition: m0/v0 accs -> B-frags (in-register pack) ----
    v8s m0B[2][4], v0B[2][4];
    #pragma unroll
    for (int st = 0; st < 2; ++st)
        #pragma unroll
        for (int kd = 0; kd < 4; ++kd) {
            v4f a0 = am[st][2 * kd], a1 = am[st][2 * kd + 1];
            v4f b0v = av[st][2 * kd], b1v = av[st][2 * kd + 1];
            m0B[st][kd] = mk8(pk2(a0[0], a0[1]), pk2(a0[2], a0[3]),
                              pk2(a1[0], a1[1]), pk2(a1[2], a1[3]));
            v0B[st][kd] = mk8(pk2(b0v[0], b0v[1]), pk2(b0v[2], b0v[3]),
                              pk2(b1v[0], b1v[1]), pk2(b1v[2], b1v[3]));
        }

    // ================= layer 1: 16 phases (2 sets x 4 ss x 2 kch) =================
    // chunk(c): ss'=c>>1, kch'=c&1 -> two 12KB pieces (kc = 2kch', 2kch'+1)
    stage_kb<12>(ws + W3, lds, w, l);
    stage_kb<12>(ws + W3 + 16 * 3072, lds + 12288, w, l);
    __syncthreads();

    #pragma unroll
    for (int st = 0; st < 2; ++st) {
        v4f m1[4] = {zf, zf, zf, zf}, v1[4] = {zf, zf, zf, zf};
        for (int ss = 0; ss < 4; ++ss) {
            v4f zz[4] = {zf, zf, zf, zf}, dd[4] = {zf, zf, zf, zf};
            for (int kch = 0; kch < 2; ++kch) {
                int p = st * 8 + ss * 2 + kch;
                char* buf = lds + (p & 1) * 24576;
                if (p < 15) {
                    int c = (p + 1) & 7;
                    int s2 = c >> 1, k2 = c & 1;
                    char* dst = lds + ((p + 1) & 1) * 24576;
                    stage_kb<12>(ws + W3 + (size_t)((2 * k2) * 16 + 4 * s2) * 3072, dst, w, l);
                    stage_kb<12>(ws + W3 + (size_t)((2 * k2 + 1) * 16 + 4 * s2) * 3072, dst + 12288, w, l);
                }
                #pragma unroll
                for (int q = 0; q < 2; ++q) {
                    int kc = 2 * kch + q;
                    #pragma unroll
                    for (int mt = 0; mt < 4; ++mt) {
                        const char* bp = buf + q * 12288 + mt * 3072 + l * 16;
                        v8s wh = *(const v8s*)bp;
                        v8s wl = *(const v8s*)(bp + 1024);
                        v8s wsq = *(const v8s*)(bp + 2048);
                        v4f a = zz[mt];
                        a = MF(wh, m0B[st][kc], a);
                        a = MF(wl, m0B[st][kc], a);
                        zz[mt] = a;
                        dd[mt] = MF(wsq, v0B[st][kc], dd[mt]);
                    }
                }
                if (kch == 1) {
                    // phi1 + G4 for this ss (A=Wm1^T from global, single-term + var)
                    #pragma unroll
                    for (int t2 = 0; t2 < 2; ++t2) {
                        int kc4 = 2 * ss + t2;
                        float4 bbA = *(const float4*)(b1 + (4 * ss + 2 * t2) * 16 + 4 * g);
                        float4 bbB = *(const float4*)(b1 + (4 * ss + 2 * t2 + 1) * 16 + 4 * g);
                        v4f zA = zz[2 * t2], zB = zz[2 * t2 + 1];
                        v4f dA = dd[2 * t2], dB = dd[2 * t2 + 1];
                        float pA[4], pB[4];
                        pA[0] = S_RFF * __cosf(zA[0] + bbA.x) * __expf(-0.5f * dA[0]);
                        pA[1] = S_RFF * __cosf(zA[1] + bbA.y) * __expf(-0.5f * dA[1]);
                        pA[2] = S_RFF * __cosf(zA[2] + bbA.z) * __expf(-0.5f * dA[2]);
                        pA[3] = S_RFF * __cosf(zA[3] + bbA.w) * __expf(-0.5f * dA[3]);
                        pB[0] = S_RFF * __cosf(zB[0] + bbB.x) * __expf(-0.5f * dB[0]);
                        pB[1] = S_RFF * __cosf(zB[1] + bbB.y) * __expf(-0.5f * dB[1]);
                        pB[2] = S_RFF * __cosf(zB[2] + bbB.z) * __expf(-0.5f * dB[2]);
                        pB[3] = S_RFF * __cosf(zB[3] + bbB.w) * __expf(-0.5f * dB[3]);
                        v8s ph = mk8(pk2(pA[0], pA[1]), pk2(pA[2], pA[3]),
                                     pk2(pB[0], pB[1]), pk2(pB[2], pB[3]));
                        v8s ps = mk8(pk2(pA[0]*pA[0], pA[1]*pA[1]), pk2(pA[2]*pA[2], pA[3]*pA[3]),
                                     pk2(pB[0]*pB[0], pB[1]*pB[1]), pk2(pB[2]*pB[2], pB[3]*pB[3]));
                        #pragma unroll
                        for (int dt = 0; dt < 4; ++dt) {
                            const char* wp = ws + W4 + (size_t)((kc4 * 4 + dt) * 2) * 1024 + l * 16;
                            v8s wh4 = *(const v8s*)wp;
                            v8s we4 = *(const v8s*)(wp + 1024);
                            m1[dt] = MF(wh4, ph, m1[dt]);
                            v1[dt] = MF(we4, ps, v1[dt]);
                        }
                    }
                }
                __syncthreads();
            }
        }
        // ---- epilogue for this set: normalize + inverse-variance atomics ----
        float s = 0.f;
        #pragma unroll
        for (int dt = 0; dt < 4; ++dt)
            #pragma unroll
            for (int qi = 0; qi < 4; ++qi)
                s = fmaf(m1[dt][qi], m1[dt][qi], s);
        s += __shfl_xor(s, 16);
        s += __shfl_xor(s, 32);
        const float inv_n = 1.0f / fmaxf(sqrtf(s), 1e-12f);
        const int p = base + st * 16 + r16;
        if (p < NPTS) {
            const int seg = xidx[p];
            const size_t ob = (size_t)seg * 64;
            #pragma unroll
            for (int dt = 0; dt < 4; ++dt)
                #pragma unroll
                for (int qi = 0; qi < 4; ++qi) {
                    const int d = dt * 16 + 4 * g + qi;
                    const float iv = 1.0f / v1[dt][qi];
                    atomicAdd(sum_inv + ob + d, iv);
                    atomicAdd(sum_wm + ob + d, iv * m1[dt][qi] * inv_n);
                }
        }
    }
}

// in-place: out0 slot holds sum_wm, out1 slot holds sum_inv
__global__ void dgp_finalize(float* __restrict__ out)
{
    const int i = blockIdx.x * blockDim.x + threadIdx.x;
    if (i < NSEG * 64) {
        const float si = out[NSEG * 64 + i];
        const float sw = out[i];
        const float ev = 1.0f / si;
        out[i] = ev * sw;
        out[NSEG * 64 + i] = ev;
    }
}

extern "C" void kernel_launch(void* const* d_in, const int* in_sizes, int n_in,
                              void* d_out, int out_size, void* d_ws, size_t ws_size,
                              hipStream_t stream)
{
    const float* x    = (const float*)d_in[0];
    const float* Om0  = (const float*)d_in[1];
    const float* b0   = (const float*)d_in[2];
    const float* Wm0  = (const float*)d_in[3];
    const float* Wlv0 = (const float*)d_in[4];
    const float* Om1  = (const float*)d_in[5];
    const float* b1   = (const float*)d_in[6];
    const float* Wm1  = (const float*)d_in[7];
    const float* Wlv1 = (const float*)d_in[8];
    const int*   xidx = (const int*)d_in[9];

    float* out = (float*)d_out;

    hipMemsetAsync(d_out, 0, (size_t)out_size * sizeof(float), stream);

    dgp_prep<<<128, 256, 0, stream>>>(Om0, Wm0, Wlv0, Om1, Wm1, Wlv1, (char*)d_ws);

    float* sum_wm  = out;               // -> output 0
    float* sum_inv = out + NSEG * 64;   // -> output 1 (embed_vars)
    const int nblk = (NPTS + 127) / 128;  // 3907
    dgp_main<<<nblk, 256, 0, stream>>>(x, xidx, b0, b1, (const char*)d_ws, sum_wm, sum_inv);

    dgp_finalize<<<(NSEG * 64 + 255) / 256, 256, 0, stream>>>(out);
}

// Round 4
// 410.655 us; speedup vs baseline: 2.2226x; 2.2226x over previous
//
#include <hip/hip_runtime.h>
#include <hip/hip_bf16.h>
#include <math.h>

#define NSEG 25000
#define NPTS 500000
#define S_RFF 0.08838834764831845f   // sqrt(2/256)

typedef __attribute__((ext_vector_type(8))) short v8s;
typedef __attribute__((ext_vector_type(4))) float v4f;

#define MF(a,b,c) __builtin_amdgcn_mfma_f32_16x16x32_bf16(a,b,c,0,0,0)

// ---- d_ws plane offsets (A-fragment order, transposed weights) ----
#define W1 0          // Om0^T  [mt 16][kcg 2][pl 2(hi,lo)] x 1KB = 64KB   (no pi)
#define W2 65536      // Wm0^T  [kc 8][mt 8][pl 3(hi,lo,E)] x 1KB = 192KB (pi)
#define W3 262144     // Om1^T  [kc 4][mt 16][pl 3(hi,lo,S)] x 1KB = 192KB (pi)
#define W4 458752     // Wm1    [kc 8][dt 4][pl 2(hi,E)] x 1KB = 64KB     (pi, used as B-frag)
// total 512KB

__device__ __forceinline__ ushort bf16_rne(float f) {
    uint u = __builtin_bit_cast(uint, f);
    u += 0x7fffu + ((u >> 16) & 1u);
    return (ushort)(u >> 16);
}
__device__ __forceinline__ float bf16f(ushort h) {
    uint u = ((uint)h) << 16;
    return __builtin_bit_cast(float, u);
}
__device__ __forceinline__ uint pk2(float a, float b) {
    __hip_bfloat162 h = __float22bfloat162_rn(make_float2(a, b));
    union { __hip_bfloat162 h; uint u; } c; c.h = h; return c.u;
}
__device__ __forceinline__ v8s mk8(uint a, uint b, uint c, uint d) {
    union { uint u[4]; v8s v; } x; x.u[0]=a; x.u[1]=b; x.u[2]=c; x.u[3]=d; return x.v;
}
__device__ __forceinline__ void unpk2(uint u, float& a, float& b) {
    a = __builtin_bit_cast(float, u << 16);
    b = __builtin_bit_cast(float, u & 0xffff0000u);
}

// slot position for k-permuted frags: far side provides k = 4g+j (j<4) / 16+4g+(j-4)
__device__ __forceinline__ int pi_el(int k32, int row) {
    int gk, j;
    if (k32 < 16) { gk = k32 >> 2; j = k32 & 3; }
    else          { gk = (k32 - 16) >> 2; j = 4 + ((k32 - 16) & 3); }
    return (gk * 16 + row) * 8 + j;
}

// ---------- prep: weights -> fragment planes ----------
__global__ void dgp_prep(const float* __restrict__ Om0, const float* __restrict__ Wm0,
                         const float* __restrict__ Wlv0, const float* __restrict__ Om1,
                         const float* __restrict__ Wm1, const float* __restrict__ Wlv1,
                         char* __restrict__ ws)
{
    const int idx = blockIdx.x * 256 + threadIdx.x;   // 0..32767
    // W1: Om0 [64][256], straight slot order (B-side x is loaded straight)
    if (idx < 16384) {
        int k = idx >> 8, c = idx & 255;
        int kcg = k >> 5, k32 = k & 31, mt = c >> 4, row = c & 15;
        int el = ((k32 >> 3) * 16 + row) * 8 + (k32 & 7);
        float v = Om0[idx];
        ushort hi = bf16_rne(v), lo = bf16_rne(v - bf16f(hi));
        ushort* p = (ushort*)(ws + W1);
        int t0 = (mt * 2 + kcg) * 2;
        p[(size_t)t0 * 512 + el] = hi;
        p[(size_t)(t0 + 1) * 512 + el] = lo;
    }
    // W2: Wm0 [256][128] + exp(Wlv0), pi
    {
        int k = idx >> 7, n = idx & 127;
        int kc = k >> 5, k32 = k & 31, mt = n >> 4, row = n & 15;
        int el = pi_el(k32, row);
        float v = Wm0[idx];
        ushort hi = bf16_rne(v), lo = bf16_rne(v - bf16f(hi));
        ushort* p = (ushort*)(ws + W2);
        int t0 = (kc * 8 + mt) * 3;
        p[(size_t)t0 * 512 + el] = hi;
        p[(size_t)(t0 + 1) * 512 + el] = lo;
        p[(size_t)(t0 + 2) * 512 + el] = bf16_rne(expf(Wlv0[idx]));
    }
    // W3: Om1 [128][256] hi/lo + Om1^2, pi
    {
        int k = idx >> 8, c = idx & 255;
        int kc = k >> 5, k32 = k & 31, mt = c >> 4, row = c & 15;
        int el = pi_el(k32, row);
        float v = Om1[idx];
        ushort hi = bf16_rne(v), lo = bf16_rne(v - bf16f(hi));
        ushort* p = (ushort*)(ws + W3);
        int t0 = (kc * 16 + mt) * 3;
        p[(size_t)t0 * 512 + el] = hi;
        p[(size_t)(t0 + 1) * 512 + el] = lo;
        p[(size_t)(t0 + 2) * 512 + el] = bf16_rne(v * v);
    }
    // W4: Wm1 [256][64] + exp(Wlv1), pi (B-fragment: slot (g,j) holds k_actual, col=d&15)
    if (idx < 16384) {
        int k = idx >> 6, d = idx & 63;
        int kc = k >> 5, k32 = k & 31, dt = d >> 4, row = d & 15;
        int el = pi_el(k32, row);
        ushort* p = (ushort*)(ws + W4);
        int t0 = (kc * 4 + dt) * 2;
        p[(size_t)t0 * 512 + el] = bf16_rne(Wm1[idx]);
        p[(size_t)(t0 + 1) * 512 + el] = bf16_rne(expf(Wlv1[idx]));
    }
}

// ---------- weight-chunk staging (global -> LDS, linear, 16B/lane) ----------
typedef __attribute__((address_space(1))) const unsigned int g_u32;
typedef __attribute__((address_space(3))) unsigned int l_u32;

template <int NKB>
__device__ __forceinline__ void stage_kb(const char* gsrc, char* dst, int w, int l) {
    #pragma unroll
    for (int i = 0; i < NKB / 4; ++i) {
        int o = (i * 4 + w) * 1024;
        __builtin_amdgcn_global_load_lds((g_u32*)(gsrc + o + l * 16),
                                         (l_u32*)(dst + o), 16, 0, 0);
    }
}

// ---------- fused main: 4 waves x 32 pts, activations never leave registers ----------
__global__ __launch_bounds__(256, 2)
void dgp_main(const float* __restrict__ x, const int* __restrict__ xidx,
              const float* __restrict__ b0, const float* __restrict__ b1,
              const char* __restrict__ ws,
              float* __restrict__ sum_wm, float* __restrict__ sum_inv)
{
    __shared__ __attribute__((aligned(16))) char lds[49152];   // 2 x 24KB ring
    const int t = threadIdx.x, l = t & 63, w = t >> 6;
    const int r16 = l & 15, g = l >> 4;
    const int base = blockIdx.x * 128 + w * 32;

    const v4f zf = {0.f, 0.f, 0.f, 0.f};

    // ---- x B-frags (hi/lo, 2 sets x 2 K-chunks) ----
    v8s xh[2][2], xl[2][2];
    #pragma unroll
    for (int st = 0; st < 2; ++st) {
        int pc = min(base + st * 16 + r16, NPTS - 1);
        #pragma unroll
        for (int kcg = 0; kcg < 2; ++kcg) {
            const float* xp = x + (size_t)pc * 64 + kcg * 32 + g * 8;
            float4 a = *(const float4*)xp;
            float4 b = *(const float4*)(xp + 4);
            uint h0 = pk2(a.x, a.y), h1 = pk2(a.z, a.w), h2 = pk2(b.x, b.y), h3 = pk2(b.z, b.w);
            float q0,q1,q2,q3,q4,q5,q6,q7;
            unpk2(h0,q0,q1); unpk2(h1,q2,q3); unpk2(h2,q4,q5); unpk2(h3,q6,q7);
            xh[st][kcg] = mk8(h0, h1, h2, h3);
            xl[st][kcg] = mk8(pk2(a.x-q0, a.y-q1), pk2(a.z-q2, a.w-q3),
                              pk2(b.x-q4, b.y-q5), pk2(b.z-q6, b.w-q7));
        }
    }

    v4f am[2][8], av[2][8];
    #pragma unroll
    for (int st = 0; st < 2; ++st)
        #pragma unroll
        for (int nt = 0; nt < 8; ++nt) { am[st][nt] = zf; av[st][nt] = zf; }

    // ================= layer 0: 8 phases (G1 mt-pair + G2 K-chunk) =================
    stage_kb<24>(ws + W2, lds, w, l);
    __syncthreads();

    for (int kc = 0; kc < 8; ++kc) {
        char* buf = lds + (kc & 1) * 24576;
        if (kc < 7)
            stage_kb<24>(ws + W2 + (size_t)(kc + 1) * 24576, lds + ((kc + 1) & 1) * 24576, w, l);

        // G1: z0^T for mt-pair {2kc, 2kc+1}; A=Om0^T from global (L1/L2-hot), 3-term
        v4f z[2][2] = {{zf, zf}, {zf, zf}};
        #pragma unroll
        for (int tt = 0; tt < 2; ++tt) {
            int mt = 2 * kc + tt;
            #pragma unroll
            for (int kcg = 0; kcg < 2; ++kcg) {
                const char* wp = ws + W1 + (size_t)((mt * 2 + kcg) * 2) * 1024 + l * 16;
                v8s ah = *(const v8s*)wp;
                v8s al = *(const v8s*)(wp + 1024);
                #pragma unroll
                for (int st = 0; st < 2; ++st) {
                    v4f a = z[st][tt];
                    a = MF(ah, xh[st][kcg], a);
                    a = MF(al, xh[st][kcg], a);
                    a = MF(ah, xl[st][kcg], a);
                    z[st][tt] = a;
                }
            }
        }
        // phi0 = s*cos(z+b0) -> B-frags (hi + sq), in-register
        float4 bbA = *(const float4*)(b0 + (2 * kc) * 16 + 4 * g);
        float4 bbB = *(const float4*)(b0 + (2 * kc + 1) * 16 + 4 * g);
        v8s ph[2], psq[2];
        #pragma unroll
        for (int st = 0; st < 2; ++st) {
            float pA[4], pB[4];
            pA[0] = S_RFF * __cosf(z[st][0][0] + bbA.x);
            pA[1] = S_RFF * __cosf(z[st][0][1] + bbA.y);
            pA[2] = S_RFF * __cosf(z[st][0][2] + bbA.z);
            pA[3] = S_RFF * __cosf(z[st][0][3] + bbA.w);
            pB[0] = S_RFF * __cosf(z[st][1][0] + bbB.x);
            pB[1] = S_RFF * __cosf(z[st][1][1] + bbB.y);
            pB[2] = S_RFF * __cosf(z[st][1][2] + bbB.z);
            pB[3] = S_RFF * __cosf(z[st][1][3] + bbB.w);
            ph[st]  = mk8(pk2(pA[0], pA[1]), pk2(pA[2], pA[3]),
                          pk2(pB[0], pB[1]), pk2(pB[2], pB[3]));
            psq[st] = mk8(pk2(pA[0]*pA[0], pA[1]*pA[1]), pk2(pA[2]*pA[2], pA[3]*pA[3]),
                          pk2(pB[0]*pB[0], pB[1]*pB[1]), pk2(pB[2]*pB[2], pB[3]*pB[3]));
        }
        // G2: m0/v0 accumulate; A=Wm0^T from LDS chunk (2-term mean + var)
        #pragma unroll
        for (int nt = 0; nt < 8; ++nt) {
            const char* bp = buf + nt * 3072 + l * 16;
            v8s wh = *(const v8s*)bp;
            v8s wl = *(const v8s*)(bp + 1024);
            v8s we = *(const v8s*)(bp + 2048);
            #pragma unroll
            for (int st = 0; st < 2; ++st) {
                v4f a = am[st][nt];
                a = MF(wh, ph[st], a);
                a = MF(wl, ph[st], a);
                am[st][nt] = a;
                av[st][nt] = MF(we, psq[st], av[st][nt]);
            }
        }
        __syncthreads();
    }

    // ---- transition: m0/v0 accs -> B-frags (in-register pack) ----
    v8s m0B[2][4], v0B[2][4];
    #pragma unroll
    for (int st = 0; st < 2; ++st)
        #pragma unroll
        for (int kd = 0; kd < 4; ++kd) {
            v4f a0 = am[st][2 * kd], a1 = am[st][2 * kd + 1];
            v4f b0v = av[st][2 * kd], b1v = av[st][2 * kd + 1];
            m0B[st][kd] = mk8(pk2(a0[0], a0[1]), pk2(a0[2], a0[3]),
                              pk2(a1[0], a1[1]), pk2(a1[2], a1[3]));
            v0B[st][kd] = mk8(pk2(b0v[0], b0v[1]), pk2(b0v[2], b0v[3]),
                              pk2(b1v[0], b1v[1]), pk2(b1v[2], b1v[3]));
        }

    // ================= layer 1: 16 phases (2 sets x 4 ss x 2 kch) =================
    stage_kb<12>(ws + W3, lds, w, l);
    stage_kb<12>(ws + W3 + 16 * 3072, lds + 12288, w, l);
    __syncthreads();

    #pragma unroll
    for (int st = 0; st < 2; ++st) {
        v4f m1[4] = {zf, zf, zf, zf}, v1[4] = {zf, zf, zf, zf};
        for (int ss = 0; ss < 4; ++ss) {
            v4f zz[4] = {zf, zf, zf, zf}, dd[4] = {zf, zf, zf, zf};
            for (int kch = 0; kch < 2; ++kch) {
                int p = st * 8 + ss * 2 + kch;
                char* buf = lds + (p & 1) * 24576;
                if (p < 15) {
                    int c = (p + 1) & 7;
                    int s2 = c >> 1, k2 = c & 1;
                    char* dst = lds + ((p + 1) & 1) * 24576;
                    stage_kb<12>(ws + W3 + (size_t)((2 * k2) * 16 + 4 * s2) * 3072, dst, w, l);
                    stage_kb<12>(ws + W3 + (size_t)((2 * k2 + 1) * 16 + 4 * s2) * 3072, dst + 12288, w, l);
                }
                #pragma unroll
                for (int q = 0; q < 2; ++q) {
                    int kc = 2 * kch + q;
                    #pragma unroll
                    for (int mt = 0; mt < 4; ++mt) {
                        const char* bp = buf + q * 12288 + mt * 3072 + l * 16;
                        v8s wh = *(const v8s*)bp;
                        v8s wl = *(const v8s*)(bp + 1024);
                        v8s wsq = *(const v8s*)(bp + 2048);
                        v4f a = zz[mt];
                        a = MF(wh, m0B[st][kc], a);
                        a = MF(wl, m0B[st][kc], a);
                        zz[mt] = a;
                        dd[mt] = MF(wsq, v0B[st][kc], dd[mt]);
                    }
                }
                if (kch == 1) {
                    // phi1 + G4 for this ss. G4 SWAPPED: A=phi1 (row=point), B=W4 (col=dim)
                    // -> C: col=lane&15=dim (contiguous per r16), row=4g+qi=point
                    #pragma unroll
                    for (int t2 = 0; t2 < 2; ++t2) {
                        int kc4 = 2 * ss + t2;
                        float4 bbA = *(const float4*)(b1 + (4 * ss + 2 * t2) * 16 + 4 * g);
                        float4 bbB = *(const float4*)(b1 + (4 * ss + 2 * t2 + 1) * 16 + 4 * g);
                        v4f zA = zz[2 * t2], zB = zz[2 * t2 + 1];
                        v4f dA = dd[2 * t2], dB = dd[2 * t2 + 1];
                        float pA[4], pB[4];
                        pA[0] = S_RFF * __cosf(zA[0] + bbA.x) * __expf(-0.5f * dA[0]);
                        pA[1] = S_RFF * __cosf(zA[1] + bbA.y) * __expf(-0.5f * dA[1]);
                        pA[2] = S_RFF * __cosf(zA[2] + bbA.z) * __expf(-0.5f * dA[2]);
                        pA[3] = S_RFF * __cosf(zA[3] + bbA.w) * __expf(-0.5f * dA[3]);
                        pB[0] = S_RFF * __cosf(zB[0] + bbB.x) * __expf(-0.5f * dB[0]);
                        pB[1] = S_RFF * __cosf(zB[1] + bbB.y) * __expf(-0.5f * dB[1]);
                        pB[2] = S_RFF * __cosf(zB[2] + bbB.z) * __expf(-0.5f * dB[2]);
                        pB[3] = S_RFF * __cosf(zB[3] + bbB.w) * __expf(-0.5f * dB[3]);
                        v8s ph = mk8(pk2(pA[0], pA[1]), pk2(pA[2], pA[3]),
                                     pk2(pB[0], pB[1]), pk2(pB[2], pB[3]));
                        v8s ps = mk8(pk2(pA[0]*pA[0], pA[1]*pA[1]), pk2(pA[2]*pA[2], pA[3]*pA[3]),
                                     pk2(pB[0]*pB[0], pB[1]*pB[1]), pk2(pB[2]*pB[2], pB[3]*pB[3]));
                        #pragma unroll
                        for (int dt = 0; dt < 4; ++dt) {
                            const char* wp = ws + W4 + (size_t)((kc4 * 4 + dt) * 2) * 1024 + l * 16;
                            v8s wh4 = *(const v8s*)wp;
                            v8s we4 = *(const v8s*)(wp + 1024);
                            m1[dt] = MF(ph, wh4, m1[dt]);
                            v1[dt] = MF(ps, we4, v1[dt]);
                        }
                    }
                }
                __syncthreads();
            }
        }
        // ---- epilogue: m1[dt] reg qi -> point 4g+qi, dim dt*16+r16 ----
        // norm: sum over the point's 64 dims = over r16-lane group (16 lanes) x 4 dt
        float s[4] = {0.f, 0.f, 0.f, 0.f};
        #pragma unroll
        for (int dt = 0; dt < 4; ++dt)
            #pragma unroll
            for (int qi = 0; qi < 4; ++qi)
                s[qi] = fmaf(m1[dt][qi], m1[dt][qi], s[qi]);
        #pragma unroll
        for (int qi = 0; qi < 4; ++qi) {
            s[qi] += __shfl_xor(s[qi], 1);
            s[qi] += __shfl_xor(s[qi], 2);
            s[qi] += __shfl_xor(s[qi], 4);
            s[qi] += __shfl_xor(s[qi], 8);
        }
        const int pbase = base + st * 16 + 4 * g;
        #pragma unroll
        for (int qi = 0; qi < 4; ++qi) {
            const int P = pbase + qi;
            if (P < NPTS) {
                const float inv_n = 1.0f / fmaxf(sqrtf(s[qi]), 1e-12f);
                const int seg = xidx[P];
                const size_t ob = (size_t)seg * 64 + r16;
                #pragma unroll
                for (int dt = 0; dt < 4; ++dt) {
                    const float iv = 1.0f / v1[dt][qi];
                    atomicAdd(sum_inv + ob + dt * 16, iv);
                    atomicAdd(sum_wm + ob + dt * 16, iv * m1[dt][qi] * inv_n);
                }
            }
        }
    }
}

// in-place: out0 slot holds sum_wm, out1 slot holds sum_inv
__global__ void dgp_finalize(float* __restrict__ out)
{
    const int i = blockIdx.x * blockDim.x + threadIdx.x;
    if (i < NSEG * 64) {
        const float si = out[NSEG * 64 + i];
        const float sw = out[i];
        const float ev = 1.0f / si;
        out[i] = ev * sw;
        out[NSEG * 64 + i] = ev;
    }
}

extern "C" void kernel_launch(void* const* d_in, const int* in_sizes, int n_in,
                              void* d_out, int out_size, void* d_ws, size_t ws_size,
                              hipStream_t stream)
{
    const float* x    = (const float*)d_in[0];
    const float* Om0  = (const float*)d_in[1];
    const float* b0   = (const float*)d_in[2];
    const float* Wm0  = (const float*)d_in[3];
    const float* Wlv0 = (const float*)d_in[4];
    const float* Om1  = (const float*)d_in[5];
    const float* b1   = (const float*)d_in[6];
    const float* Wm1  = (const float*)d_in[7];
    const float* Wlv1 = (const float*)d_in[8];
    const int*   xidx = (const int*)d_in[9];

    float* out = (float*)d_out;

    hipMemsetAsync(d_out, 0, (size_t)out_size * sizeof(float), stream);

    dgp_prep<<<128, 256, 0, stream>>>(Om0, Wm0, Wlv0, Om1, Wm1, Wlv1, (char*)d_ws);

    float* sum_wm  = out;               // -> output 0
    float* sum_inv = out + NSEG * 64;   // -> output 1 (embed_vars)
    const int nblk = (NPTS + 127) / 128;  // 3907
    dgp_main<<<nblk, 256, 0, stream>>>(x, xidx, b0, b1, (const char*)d_ws, sum_wm, sum_inv);

    dgp_finalize<<<(NSEG * 64 + 255) / 256, 256, 0, stream>>>(out);
}

// Round 5
// 401.586 us; speedup vs baseline: 2.2728x; 1.0226x over previous
//
#include <hip/hip_runtime.h>
#include <hip/hip_bf16.h>
#include <math.h>

#define NSEG 25000
#define NPTS 500000
#define S_RFF 0.08838834764831845f   // sqrt(2/256)

typedef __attribute__((ext_vector_type(8))) short v8s;
typedef __attribute__((ext_vector_type(4))) float v4f;

#define MF(a,b,c) __builtin_amdgcn_mfma_f32_16x16x32_bf16(a,b,c,0,0,0)

// ---- d_ws plane offsets (fragment order; identical to round 4) ----
#define W1 0          // Om0^T  [mt 16][kcg 2][pl 2(hi,lo)] x 1KB = 64KB   (no pi)
#define W2 65536      // Wm0^T  [kc 8][mt 8][pl 3(hi,lo,E)] x 1KB = 192KB (pi)
#define W3 262144     // Om1^T  [kc 4][mt 16][pl 3(hi,lo,S)] x 1KB = 192KB (pi)
#define W4 458752     // Wm1    [kc 8][dt 4][pl 2(hi,E)] x 1KB = 64KB     (pi, B-frag)

__device__ __forceinline__ ushort bf16_rne(float f) {
    uint u = __builtin_bit_cast(uint, f);
    u += 0x7fffu + ((u >> 16) & 1u);
    return (ushort)(u >> 16);
}
__device__ __forceinline__ float bf16f(ushort h) {
    uint u = ((uint)h) << 16;
    return __builtin_bit_cast(float, u);
}
__device__ __forceinline__ uint pk2(float a, float b) {
    __hip_bfloat162 h = __float22bfloat162_rn(make_float2(a, b));
    union { __hip_bfloat162 h; uint u; } c; c.h = h; return c.u;
}
__device__ __forceinline__ v8s mk8(uint a, uint b, uint c, uint d) {
    union { uint u[4]; v8s v; } x; x.u[0]=a; x.u[1]=b; x.u[2]=c; x.u[3]=d; return x.v;
}
__device__ __forceinline__ void unpk2(uint u, float& a, float& b) {
    a = __builtin_bit_cast(float, u << 16);
    b = __builtin_bit_cast(float, u & 0xffff0000u);
}

// slot position for k-permuted frags: far side provides k = 4g+j (j<4) / 16+4g+(j-4)
__device__ __forceinline__ int pi_el(int k32, int row) {
    int gk, j;
    if (k32 < 16) { gk = k32 >> 2; j = k32 & 3; }
    else          { gk = (k32 - 16) >> 2; j = 4 + ((k32 - 16) & 3); }
    return (gk * 16 + row) * 8 + j;
}

// ---------- prep: weights -> fragment planes (unchanged from round 4) ----------
__global__ void dgp_prep(const float* __restrict__ Om0, const float* __restrict__ Wm0,
                         const float* __restrict__ Wlv0, const float* __restrict__ Om1,
                         const float* __restrict__ Wm1, const float* __restrict__ Wlv1,
                         char* __restrict__ ws)
{
    const int idx = blockIdx.x * 256 + threadIdx.x;   // 0..32767
    if (idx < 16384) {
        int k = idx >> 8, c = idx & 255;
        int kcg = k >> 5, k32 = k & 31, mt = c >> 4, row = c & 15;
        int el = ((k32 >> 3) * 16 + row) * 8 + (k32 & 7);
        float v = Om0[idx];
        ushort hi = bf16_rne(v), lo = bf16_rne(v - bf16f(hi));
        ushort* p = (ushort*)(ws + W1);
        int t0 = (mt * 2 + kcg) * 2;
        p[(size_t)t0 * 512 + el] = hi;
        p[(size_t)(t0 + 1) * 512 + el] = lo;
    }
    {
        int k = idx >> 7, n = idx & 127;
        int kc = k >> 5, k32 = k & 31, mt = n >> 4, row = n & 15;
        int el = pi_el(k32, row);
        float v = Wm0[idx];
        ushort hi = bf16_rne(v), lo = bf16_rne(v - bf16f(hi));
        ushort* p = (ushort*)(ws + W2);
        int t0 = (kc * 8 + mt) * 3;
        p[(size_t)t0 * 512 + el] = hi;
        p[(size_t)(t0 + 1) * 512 + el] = lo;
        p[(size_t)(t0 + 2) * 512 + el] = bf16_rne(expf(Wlv0[idx]));
    }
    {
        int k = idx >> 8, c = idx & 255;
        int kc = k >> 5, k32 = k & 31, mt = c >> 4, row = c & 15;
        int el = pi_el(k32, row);
        float v = Om1[idx];
        ushort hi = bf16_rne(v), lo = bf16_rne(v - bf16f(hi));
        ushort* p = (ushort*)(ws + W3);
        int t0 = (kc * 16 + mt) * 3;
        p[(size_t)t0 * 512 + el] = hi;
        p[(size_t)(t0 + 1) * 512 + el] = lo;
        p[(size_t)(t0 + 2) * 512 + el] = bf16_rne(v * v);
    }
    if (idx < 16384) {
        int k = idx >> 6, d = idx & 63;
        int kc = k >> 5, k32 = k & 31, dt = d >> 4, row = d & 15;
        int el = pi_el(k32, row);
        ushort* p = (ushort*)(ws + W4);
        int t0 = (kc * 4 + dt) * 2;
        p[(size_t)t0 * 512 + el] = bf16_rne(Wm1[idx]);
        p[(size_t)(t0 + 1) * 512 + el] = bf16_rne(expf(Wlv1[idx]));
    }
}

// ---------- weight-chunk staging (global -> LDS, linear, 16B/lane, 8 waves) ----------
typedef __attribute__((address_space(1))) const unsigned int g_u32;
typedef __attribute__((address_space(3))) unsigned int l_u32;

template <int NKB>
__device__ __forceinline__ void stage_kb(const char* gsrc, char* dst, int w, int l) {
    #pragma unroll
    for (int i = 0; i < (NKB + 7) / 8; ++i) {
        const int idx = i * 8 + w;
        if (idx < NKB)
            __builtin_amdgcn_global_load_lds((g_u32*)(gsrc + idx * 1024 + l * 16),
                                             (l_u32*)(dst + idx * 1024), 16, 0, 0);
    }
}

// ---------- fused main: 8 waves x 16 pts, activations never leave registers ----------
__global__ __launch_bounds__(512, 4)
void dgp_main(const float* __restrict__ x, const int* __restrict__ xidx,
              const float* __restrict__ b0, const float* __restrict__ b1,
              const char* __restrict__ ws,
              float* __restrict__ sum_wm, float* __restrict__ sum_inv)
{
    __shared__ __attribute__((aligned(16))) char lds[49152];   // 2 x 24KB ring
    const int t = threadIdx.x, l = t & 63, w = t >> 6;          // w 0..7
    const int r16 = l & 15, g = l >> 4;
    const int base = blockIdx.x * 128 + w * 16;

    const v4f zf = {0.f, 0.f, 0.f, 0.f};

    // ---- x B-frags (hi/lo, 2 K-chunks), 16 pts per wave ----
    v8s xh[2], xl[2];
    {
        const int pc = min(base + r16, NPTS - 1);
        #pragma unroll
        for (int kcg = 0; kcg < 2; ++kcg) {
            const float* xp = x + (size_t)pc * 64 + kcg * 32 + g * 8;
            float4 a = *(const float4*)xp;
            float4 b = *(const float4*)(xp + 4);
            uint h0 = pk2(a.x, a.y), h1 = pk2(a.z, a.w), h2 = pk2(b.x, b.y), h3 = pk2(b.z, b.w);
            float q0,q1,q2,q3,q4,q5,q6,q7;
            unpk2(h0,q0,q1); unpk2(h1,q2,q3); unpk2(h2,q4,q5); unpk2(h3,q6,q7);
            xh[kcg] = mk8(h0, h1, h2, h3);
            xl[kcg] = mk8(pk2(a.x-q0, a.y-q1), pk2(a.z-q2, a.w-q3),
                          pk2(b.x-q4, b.y-q5), pk2(b.z-q6, b.w-q7));
        }
    }

    v4f am[8], av[8];
    #pragma unroll
    for (int nt = 0; nt < 8; ++nt) { am[nt] = zf; av[nt] = zf; }

    // ================= layer 0: 8 phases (G1 mt-pair + G2 K-chunk) =================
    stage_kb<24>(ws + W2, lds, w, l);
    __syncthreads();

    for (int kc = 0; kc < 8; ++kc) {
        char* buf = lds + (kc & 1) * 24576;
        char* nxt = lds + ((kc + 1) & 1) * 24576;
        if (kc < 7) {
            stage_kb<24>(ws + W2 + (size_t)(kc + 1) * 24576, nxt, w, l);
        } else {
            // cross-over: prefetch layer-1 chunk 0 (ss=0, kch=0)
            stage_kb<12>(ws + W3, nxt, w, l);
            stage_kb<12>(ws + W3 + 16 * 3072, nxt + 12288, w, l);
        }

        // G1: z0^T for mt-pair {2kc, 2kc+1}; A=Om0^T direct from global (L1-hot), 3-term
        v4f z[2] = {zf, zf};
        #pragma unroll
        for (int tt = 0; tt < 2; ++tt) {
            const int mt = 2 * kc + tt;
            #pragma unroll
            for (int kcg = 0; kcg < 2; ++kcg) {
                const char* wp = ws + W1 + (size_t)((mt * 2 + kcg) * 2) * 1024 + l * 16;
                v8s ah = *(const v8s*)wp;
                v8s al = *(const v8s*)(wp + 1024);
                v4f a = z[tt];
                a = MF(ah, xh[kcg], a);
                a = MF(al, xh[kcg], a);
                a = MF(ah, xl[kcg], a);
                z[tt] = a;
            }
        }
        // phi0 = s*cos(z+b0) -> B-frags (hi + sq), in-register
        float4 bbA = *(const float4*)(b0 + (2 * kc) * 16 + 4 * g);
        float4 bbB = *(const float4*)(b0 + (2 * kc + 1) * 16 + 4 * g);
        float pA[4], pB[4];
        pA[0] = S_RFF * __cosf(z[0][0] + bbA.x);
        pA[1] = S_RFF * __cosf(z[0][1] + bbA.y);
        pA[2] = S_RFF * __cosf(z[0][2] + bbA.z);
        pA[3] = S_RFF * __cosf(z[0][3] + bbA.w);
        pB[0] = S_RFF * __cosf(z[1][0] + bbB.x);
        pB[1] = S_RFF * __cosf(z[1][1] + bbB.y);
        pB[2] = S_RFF * __cosf(z[1][2] + bbB.z);
        pB[3] = S_RFF * __cosf(z[1][3] + bbB.w);
        v8s ph  = mk8(pk2(pA[0], pA[1]), pk2(pA[2], pA[3]),
                      pk2(pB[0], pB[1]), pk2(pB[2], pB[3]));
        v8s psq = mk8(pk2(pA[0]*pA[0], pA[1]*pA[1]), pk2(pA[2]*pA[2], pA[3]*pA[3]),
                      pk2(pB[0]*pB[0], pB[1]*pB[1]), pk2(pB[2]*pB[2], pB[3]*pB[3]));

        // G2: m0/v0 accumulate; A=Wm0^T from LDS chunk (2-term mean + var)
        #pragma unroll
        for (int nt = 0; nt < 8; ++nt) {
            const char* bp = buf + nt * 3072 + l * 16;
            v8s wh = *(const v8s*)bp;
            v8s wl = *(const v8s*)(bp + 1024);
            v8s we = *(const v8s*)(bp + 2048);
            v4f a = am[nt];
            a = MF(wh, ph, a);
            a = MF(wl, ph, a);
            am[nt] = a;
            av[nt] = MF(we, psq, av[nt]);
        }
        __syncthreads();
    }

    // ---- transition: m0/v0 accs -> B-frags (in-register pack) ----
    v8s m0B[4], v0B[4];
    #pragma unroll
    for (int kd = 0; kd < 4; ++kd) {
        v4f a0 = am[2 * kd], a1 = am[2 * kd + 1];
        v4f b0v = av[2 * kd], b1v = av[2 * kd + 1];
        m0B[kd] = mk8(pk2(a0[0], a0[1]), pk2(a0[2], a0[3]),
                      pk2(a1[0], a1[1]), pk2(a1[2], a1[3]));
        v0B[kd] = mk8(pk2(b0v[0], b0v[1]), pk2(b0v[2], b0v[3]),
                      pk2(b1v[0], b1v[1]), pk2(b1v[2], b1v[3]));
    }

    // ================= layer 1: 8 phases (4 ss x 2 kch), W3 staged ONCE =================
    v4f m1[4] = {zf, zf, zf, zf}, v1[4] = {zf, zf, zf, zf};
    for (int ss = 0; ss < 4; ++ss) {
        v4f zz[4] = {zf, zf, zf, zf}, dd[4] = {zf, zf, zf, zf};
        #pragma unroll
        for (int kch = 0; kch < 2; ++kch) {
            const int p = ss * 2 + kch;
            char* buf = lds + (p & 1) * 24576;
            if (p < 7) {
                const int c = p + 1;
                const int s2 = c >> 1, k2 = c & 1;
                char* dst = lds + ((p + 1) & 1) * 24576;
                stage_kb<12>(ws + W3 + (size_t)((2 * k2) * 16 + 4 * s2) * 3072, dst, w, l);
                stage_kb<12>(ws + W3 + (size_t)((2 * k2 + 1) * 16 + 4 * s2) * 3072, dst + 12288, w, l);
            }
            #pragma unroll
            for (int q = 0; q < 2; ++q) {
                const int kcq = 2 * kch + q;
                #pragma unroll
                for (int mt = 0; mt < 4; ++mt) {
                    const char* bp = buf + q * 12288 + mt * 3072 + l * 16;
                    v8s wh = *(const v8s*)bp;
                    v8s wl = *(const v8s*)(bp + 1024);
                    v8s wsq = *(const v8s*)(bp + 2048);
                    v4f a = zz[mt];
                    a = MF(wh, m0B[kcq], a);
                    a = MF(wl, m0B[kcq], a);
                    zz[mt] = a;
                    dd[mt] = MF(wsq, v0B[kcq], dd[mt]);
                }
            }
            if (kch == 1) {
                // phi1 + G4. G4 swapped: A=phi1 (row=point), B=W4 (col=dim)
                #pragma unroll
                for (int t2 = 0; t2 < 2; ++t2) {
                    const int kc4 = 2 * ss + t2;
                    float4 bbA = *(const float4*)(b1 + (4 * ss + 2 * t2) * 16 + 4 * g);
                    float4 bbB = *(const float4*)(b1 + (4 * ss + 2 * t2 + 1) * 16 + 4 * g);
                    v4f zA = zz[2 * t2], zB = zz[2 * t2 + 1];
                    v4f dA = dd[2 * t2], dB = dd[2 * t2 + 1];
                    float pA[4], pB[4];
                    pA[0] = S_RFF * __cosf(zA[0] + bbA.x) * __expf(-0.5f * dA[0]);
                    pA[1] = S_RFF * __cosf(zA[1] + bbA.y) * __expf(-0.5f * dA[1]);
                    pA[2] = S_RFF * __cosf(zA[2] + bbA.z) * __expf(-0.5f * dA[2]);
                    pA[3] = S_RFF * __cosf(zA[3] + bbA.w) * __expf(-0.5f * dA[3]);
                    pB[0] = S_RFF * __cosf(zB[0] + bbB.x) * __expf(-0.5f * dB[0]);
                    pB[1] = S_RFF * __cosf(zB[1] + bbB.y) * __expf(-0.5f * dB[1]);
                    pB[2] = S_RFF * __cosf(zB[2] + bbB.z) * __expf(-0.5f * dB[2]);
                    pB[3] = S_RFF * __cosf(zB[3] + bbB.w) * __expf(-0.5f * dB[3]);
                    v8s ph = mk8(pk2(pA[0], pA[1]), pk2(pA[2], pA[3]),
                                 pk2(pB[0], pB[1]), pk2(pB[2], pB[3]));
                    v8s ps = mk8(pk2(pA[0]*pA[0], pA[1]*pA[1]), pk2(pA[2]*pA[2], pA[3]*pA[3]),
                                 pk2(pB[0]*pB[0], pB[1]*pB[1]), pk2(pB[2]*pB[2], pB[3]*pB[3]));
                    #pragma unroll
                    for (int dt = 0; dt < 4; ++dt) {
                        const char* wp = ws + W4 + (size_t)((kc4 * 4 + dt) * 2) * 1024 + l * 16;
                        v8s wh4 = *(const v8s*)wp;
                        v8s we4 = *(const v8s*)(wp + 1024);
                        m1[dt] = MF(ph, wh4, m1[dt]);
                        v1[dt] = MF(ps, we4, v1[dt]);
                    }
                }
            }
            __syncthreads();
        }
    }

    // ---- epilogue: m1[dt] reg qi -> point 4g+qi, dim dt*16+r16; merged atomics ----
    float s[4] = {0.f, 0.f, 0.f, 0.f};
    #pragma unroll
    for (int dt = 0; dt < 4; ++dt)
        #pragma unroll
        for (int qi = 0; qi < 4; ++qi)
            s[qi] = fmaf(m1[dt][qi], m1[dt][qi], s[qi]);
    #pragma unroll
    for (int qi = 0; qi < 4; ++qi) {
        s[qi] += __shfl_xor(s[qi], 1);
        s[qi] += __shfl_xor(s[qi], 2);
        s[qi] += __shfl_xor(s[qi], 4);
        s[qi] += __shfl_xor(s[qi], 8);
    }
    const int pbase = base + 4 * g;
    #pragma unroll
    for (int qi = 0; qi < 4; ++qi) {
        const int P = pbase + qi;
        if (P < NPTS) {
            const float inv_n = 1.0f / fmaxf(sqrtf(s[qi]), 1e-12f);
            const int seg = xidx[P];
            const size_t ob = (size_t)seg * 64 + r16;
            #pragma unroll
            for (int dt = 0; dt < 4; ++dt) {
                const float iv = 1.0f / v1[dt][qi];
                atomicAdd(sum_inv + ob + dt * 16, iv);
                atomicAdd(sum_wm + ob + dt * 16, iv * m1[dt][qi] * inv_n);
            }
        }
    }
}

// in-place: out0 slot holds sum_wm, out1 slot holds sum_inv
__global__ void dgp_finalize(float* __restrict__ out)
{
    const int i = blockIdx.x * blockDim.x + threadIdx.x;
    if (i < NSEG * 64) {
        const float si = out[NSEG * 64 + i];
        const float sw = out[i];
        const float ev = 1.0f / si;
        out[i] = ev * sw;
        out[NSEG * 64 + i] = ev;
    }
}

extern "C" void kernel_launch(void* const* d_in, const int* in_sizes, int n_in,
                              void* d_out, int out_size, void* d_ws, size_t ws_size,
                              hipStream_t stream)
{
    const float* x    = (const float*)d_in[0];
    const float* Om0  = (const float*)d_in[1];
    const float* b0   = (const float*)d_in[2];
    const float* Wm0  = (const float*)d_in[3];
    const float* Wlv0 = (const float*)d_in[4];
    const float* Om1  = (const float*)d_in[5];
    const float* b1   = (const float*)d_in[6];
    const float* Wm1  = (const float*)d_in[7];
    const float* Wlv1 = (const float*)d_in[8];
    const int*   xidx = (const int*)d_in[9];

    float* out = (float*)d_out;

    hipMemsetAsync(d_out, 0, (size_t)out_size * sizeof(float), stream);

    dgp_prep<<<128, 256, 0, stream>>>(Om0, Wm0, Wlv0, Om1, Wm1, Wlv1, (char*)d_ws);

    float* sum_wm  = out;               // -> output 0
    float* sum_inv = out + NSEG * 64;   // -> output 1 (embed_vars)
    const int nblk = (NPTS + 127) / 128;  // 3907 blocks x 512 threads (8 waves x 16 pts)
    dgp_main<<<nblk, 512, 0, stream>>>(x, xidx, b0, b1, (const char*)d_ws, sum_wm, sum_inv);

    dgp_finalize<<<(NSEG * 64 + 255) / 256, 256, 0, stream>>>(out);
}